// Round 11
// baseline (1105.382 us; speedup 1.0000x reference)
//
#include <hip/hip_runtime.h>
#include <hip/hip_bf16.h>
#include <hip/hip_cooperative_groups.h>

namespace cg = cooperative_groups;

// InfiniteNeuralNetwork: the scan state stays row-constant, so
//   p[j] = (1/D) * prod_{d,k} cos^2(inf_w[d,j,k])
// and each infinite layer is just tanh(x @ cls_w + cls_b + p).
// Network = 6 GEMMs [2048x2048x2048] with fused epilogues.
// R3: XOR-swizzle fixed 16-way LDS conflicts (93 -> ~41us/GEMM).
// R4: depth-3 counted-vmcnt pipeline (~35us/GEMM). 1 block/CU.
// R5: BN=64/BK=32, 512 blocks = 2/CU. 247us.
// R6: LDS-repacked 16B-store epilogue + setprio(1). 219us.
// R7/R9: one barrier per K-step (4 bufs) - neutral (221us).
// R10: B global->reg streaming FAILED: 16B loads at 4KB stride =
//      4x overfetch (FETCH 62MB), latency-bound, 85us/GEMM. Reverted.
// R11: ONE cooperative kernel: prep phase + 6 GEMM phases with
//      grid.sync() between layers. Kills 7 dispatch gaps + tails.

#define DD 2048
#define DEPTH 9

#define BM 128
#define BN 64
#define BK 32
#define NT (DD / BK)     // 64 K-tiles
#define ABUF (BM * BK)   // elements per A LDS buffer
#define BBUF (BN * BK)   // elements per B LDS buffer
#define DDe ((size_t)DD * DD)

typedef __attribute__((ext_vector_type(8))) short short8;
typedef __attribute__((ext_vector_type(4))) float f32x4;

__device__ __forceinline__ unsigned short f2bf(float f) {
  unsigned u = __float_as_uint(f);
  u += 0x7FFFu + ((u >> 16) & 1u);   // round-to-nearest-even
  return (unsigned short)(u >> 16);
}

__device__ __forceinline__ void gload_lds16(const unsigned short* g,
                                            unsigned short* l) {
  __builtin_amdgcn_global_load_lds(
      (const __attribute__((address_space(1))) void*)g,
      (__attribute__((address_space(3))) void*)l, 16, 0, 0);
}

struct Params {
  const float *x, *w0, *b0, *w1, *b1, *infw1, *clsw1, *clsb1;
  const float *w2, *b2, *infw2, *clsw2, *clsb2, *w3, *b3;
  float* out;
  unsigned short *buf0, *buf1, *wts;
  float *padd1, *padd2;
};

__global__ __launch_bounds__(256, 2) void fused_kernel(Params p) {
  // 48KB union: 4 x (8KB A + 4KB B) pipeline bufs / epilogue f32 tile
  // (128*68*4 = 34816B) / prep transpose tile (32*33*4 = 4224B).
  __shared__ __align__(16) unsigned char smem[49152];
  unsigned short* As = (unsigned short*)smem;                  // 4 x 4096 el
  unsigned short* Bs = (unsigned short*)(smem + 4 * ABUF * 2); // 4 x 2048 el

  int tid = threadIdx.x;
  int bid = blockIdx.x;

  // ---------------- phase 0: prep (grid-strided) ----------------
  {
    float* tile = reinterpret_cast<float*>(smem);  // [32][33] f32
    int tx = tid & 31, ty = tid >> 5;
#pragma unroll 1
    for (int ti = bid; ti < 6 * 4096; ti += 512) {
      int z = ti >> 12, t = ti & 4095;
      const float* src = z == 0 ? p.w0 : z == 1 ? p.w1 : z == 2 ? p.clsw1
                       : z == 3 ? p.w2 : z == 4 ? p.clsw2 : p.w3;
      unsigned short* dst = p.wts + (size_t)z * DDe;
      int bx = (t & 63) * 32;   // n base
      int by = (t >> 6) * 32;   // k base
      __syncthreads();          // protect prev iter's reads
#pragma unroll
      for (int i = ty; i < 32; i += 8)
        tile[i * 33 + tx] = src[(size_t)(by + i) * DD + bx + tx];
      __syncthreads();
#pragma unroll
      for (int i = ty; i < 32; i += 8)
        dst[(size_t)(bx + i) * DD + by + tx] = f2bf(tile[tx * 33 + i]);
    }
  }
  // x -> bf16 (1,048,576 float4 chunks, 8 per thread)
#pragma unroll 1
  for (int i = bid * 256 + tid; i < DD * DD / 4; i += 512 * 256) {
    float4 v = reinterpret_cast<const float4*>(p.x)[i];
    ushort4 o;
    o.x = f2bf(v.x); o.y = f2bf(v.y); o.z = f2bf(v.z); o.w = f2bf(v.w);
    reinterpret_cast<ushort4*>(p.buf0)[i] = o;
  }
  // padd[j] = cls_b[j] + (1/D) * prod cos^2 (both infinite layers)
  if (bid < 16) {
    int jj = bid * 256 + tid;   // 0..4095
    int ly = jj >> 11, j = jj & 2047;
    const float* inf_w = ly ? p.infw2 : p.infw1;
    const float* cls_b = ly ? p.clsb2 : p.clsb1;
    float* padd = ly ? p.padd2 : p.padd1;
    float prod = 1.0f;
#pragma unroll
    for (int d = 0; d < DEPTH; ++d) {
      const float* row = inf_w + ((size_t)d * DD + j) * DD;
      prod *= cosf(row[0]) * cosf(row[1]) * cosf(row[2]);
    }
    padd[j] = cls_b[j] + prod * prod * (1.0f / (float)DD);
  }
  __threadfence();
  cg::this_grid().sync();
  __threadfence();

  // ---------------- GEMM phases ----------------
  int wid = tid >> 6, lane = tid & 63;
  int wr = wid >> 1, wc = wid & 1;   // wave grid 2x2, wave tile 64x32
  int lr = lane & 15;
  int lg = lane >> 4;

  // XCD-aware bijective swizzle over 512 blocks (512 % 8 == 0).
  int swz = (bid & 7) * 64 + (bid >> 3);
  int bcol = (swz & 31) * BN;   // 32 n-tiles
  int brow = (swz >> 5) * BM;   // 16 m-tiles

#pragma unroll 1
  for (int layer = 0; layer < 6; ++layer) {
    const unsigned short* A = (layer & 1) ? p.buf1 : p.buf0;
    unsigned short* Cb = (layer & 1) ? p.buf0 : p.buf1;
    const unsigned short* Bt = p.wts + (size_t)layer * DDe;
    const float* bias = layer == 0 ? p.b0 : layer == 1 ? p.b1
                      : layer == 2 ? p.padd1 : layer == 3 ? p.b2
                      : layer == 4 ? p.padd2 : p.b3;
    int epi = (layer == 2 || layer == 4) ? 1 : (layer == 5 ? 2 : 0);

    const unsigned short* Abase = A + (size_t)brow * DD;
    const unsigned short* Bbase = Bt + (size_t)bcol * DD;

    // Staging (rule 21): LDS dest linear; SOURCE slot pre-swizzled with
    // the reader's involution slot' = slot ^ ((row>>1)&3). 3 loads/thread.
    auto stage = [&](int buf, int tile_) {
      int kt = tile_ * BK;
#pragma unroll
      for (int r = 0; r < 2; ++r) {
        int chunk = r * 256 + tid;        // A: 128 rows x 4 slots
        int row = chunk >> 2;
        int sp = chunk & 3;
        int kof = (sp ^ ((row >> 1) & 3)) * 8;
        gload_lds16(Abase + (size_t)row * DD + kt + kof,
                    As + buf * ABUF + (size_t)(r * 256 + wid * 64) * 8);
      }
      {
        int row = tid >> 2;               // B: 64 rows x 4 slots
        int sp = tid & 3;
        int kof = (sp ^ ((row >> 1) & 3)) * 8;
        gload_lds16(Bbase + (size_t)row * DD + kt + kof,
                    Bs + buf * BBUF + (size_t)(wid * 64) * 8);
      }
    };

    f32x4 acc[4][2];
#pragma unroll
    for (int i = 0; i < 4; ++i)
#pragma unroll
      for (int j = 0; j < 2; ++j) acc[i][j] = f32x4{0.f, 0.f, 0.f, 0.f};

    auto compute = [&](int buf) {
      short8 a[4], b[2];
#pragma unroll
      for (int mt = 0; mt < 4; ++mt) {
        int row = wr * 64 + mt * 16 + lr;
        int slot = lg ^ ((row >> 1) & 3);
        a[mt] = *reinterpret_cast<const short8*>(
            &As[buf * ABUF + row * BK + slot * 8]);
      }
#pragma unroll
      for (int nt = 0; nt < 2; ++nt) {
        int row = wc * 32 + nt * 16 + lr;
        int slot = lg ^ ((row >> 1) & 3);
        b[nt] = *reinterpret_cast<const short8*>(
            &Bs[buf * BBUF + row * BK + slot * 8]);
      }
      __builtin_amdgcn_s_setprio(1);       // T5
#pragma unroll
      for (int mt = 0; mt < 4; ++mt)
#pragma unroll
        for (int nt = 0; nt < 2; ++nt)
          acc[mt][nt] = __builtin_amdgcn_mfma_f32_16x16x32_bf16(
              a[mt], b[nt], acc[mt][nt], 0, 0, 0);
      __builtin_amdgcn_s_setprio(0);
    };

    // ONE barrier per step; tile t lives in buf t&3 (R9-verified schedule).
    auto step = [&](int buf, int pf_tile, int wcase) {
      if (wcase == 0) asm volatile("s_waitcnt vmcnt(6)" ::: "memory");
      else if (wcase == 1) asm volatile("s_waitcnt vmcnt(3)" ::: "memory");
      else asm volatile("s_waitcnt vmcnt(0)" ::: "memory");
      __builtin_amdgcn_s_barrier();        // buffer `buf` fully written
      __builtin_amdgcn_sched_barrier(0);
      compute(buf);
      if (pf_tile < NT) stage(pf_tile & 3, pf_tile);
    };

    stage(0, 0); stage(1, 1); stage(2, 2);   // 9 loads/thread in flight
#pragma unroll 1
    for (int i = 0; i < 15; ++i) {           // steps 0..59
      int t = 4 * i;
      step(0, t + 3, 0);
      step(1, t + 4, 0);
      step(2, t + 5, 0);
      step(3, t + 6, 0);
    }
    step(0, 63, 0);                          // step 60: prefetch tile 63
    step(1, NT, 0);                          // step 61
    step(2, NT, 1);                          // step 62
    step(3, NT, 2);                          // step 63

    // ---- epilogue: LDS-repack to coalesced 16B stores.
    // C/D layout col=lane&15, row=(lane>>4)*4+reg [m89-verified].
    {
      float* et = reinterpret_cast<float*>(smem);   // [128][68] f32
      __syncthreads();                              // pipeline LDS dead
#pragma unroll
      for (int nt = 0; nt < 2; ++nt) {
        int colb = wc * 32 + nt * 16 + lr;
        float bs = bias[bcol + colb];
#pragma unroll
        for (int mt = 0; mt < 4; ++mt) {
#pragma unroll
          for (int i = 0; i < 4; ++i) {
            int rowb = wr * 64 + mt * 16 + lg * 4 + i;
            float v = acc[mt][nt][i] + bs;
            v = (epi == 1) ? tanhf(v) : fmaxf(v, 0.0f);
            et[rowb * 68 + colb] = v;
          }
        }
      }
      __syncthreads();
#pragma unroll
      for (int it = 0; it < 4; ++it) {
        int chunk = it * 256 + tid;          // 1024 chunks of 8 elements
        int rowb = chunk >> 3;
        int c8 = (chunk & 7) * 8;
        float4 v0 = *reinterpret_cast<const float4*>(&et[rowb * 68 + c8]);
        float4 v1 = *reinterpret_cast<const float4*>(&et[rowb * 68 + c8 + 4]);
        size_t g = (size_t)(brow + rowb) * DD + bcol + c8;
        if (epi == 2) {
          *reinterpret_cast<float4*>(&p.out[g]) = v0;
          *reinterpret_cast<float4*>(&p.out[g + 4]) = v1;
        } else {
          uint4 o;
          o.x = (unsigned)f2bf(v0.x) | ((unsigned)f2bf(v0.y) << 16);
          o.y = (unsigned)f2bf(v0.z) | ((unsigned)f2bf(v0.w) << 16);
          o.z = (unsigned)f2bf(v1.x) | ((unsigned)f2bf(v1.y) << 16);
          o.w = (unsigned)f2bf(v1.z) | ((unsigned)f2bf(v1.w) << 16);
          *reinterpret_cast<uint4*>(&Cb[g]) = o;
        }
      }
    }
    if (layer != 5) {
      __threadfence();                 // release (wb L2)
      cg::this_grid().sync();
      __threadfence();                 // acquire (inv L1/L2)
    }
  }
}

// ---------------- launch ----------------

extern "C" void kernel_launch(void* const* d_in, const int* in_sizes, int n_in,
                              void* d_out, int out_size, void* d_ws,
                              size_t ws_size, hipStream_t stream) {
  char* ws = (char*)d_ws;
  const size_t MB = 1ull << 20;

  Params prm;
  prm.x     = (const float*)d_in[0];
  prm.w0    = (const float*)d_in[1];
  prm.b0    = (const float*)d_in[2];
  prm.w1    = (const float*)d_in[3];
  prm.b1    = (const float*)d_in[4];
  prm.infw1 = (const float*)d_in[5];
  prm.clsw1 = (const float*)d_in[6];
  prm.clsb1 = (const float*)d_in[7];
  prm.w2    = (const float*)d_in[8];
  prm.b2    = (const float*)d_in[9];
  prm.infw2 = (const float*)d_in[10];
  prm.clsw2 = (const float*)d_in[11];
  prm.clsb2 = (const float*)d_in[12];
  prm.w3    = (const float*)d_in[13];
  prm.b3    = (const float*)d_in[14];
  prm.out   = (float*)d_out;
  prm.buf0  = (unsigned short*)ws;              // 8 MB (x bf16 / act)
  prm.buf1  = (unsigned short*)(ws + 8 * MB);   // 8 MB (act)
  prm.wts   = (unsigned short*)(ws + 16 * MB);  // 6 x 8 MB
  prm.padd1 = (float*)(ws + 64 * MB);
  prm.padd2 = prm.padd1 + DD;

  void* args[] = {&prm};
  hipLaunchCooperativeKernel((const void*)fused_kernel, dim3(512), dim3(256),
                             args, 0, stream);
}

// Round 12
// 222.016 us; speedup vs baseline: 4.9788x; 4.9788x over previous
//
#include <hip/hip_runtime.h>
#include <hip/hip_bf16.h>

// InfiniteNeuralNetwork: the scan state stays row-constant, so
//   p[j] = (1/D) * prod_{d,k} cos^2(inf_w[d,j,k])
// and each infinite layer is just tanh(x @ cls_w + cls_b + p).
// Network = 6 GEMMs [2048x2048x2048] with fused epilogues.
// R3: XOR-swizzle fixed 16-way LDS conflicts (93 -> ~41us/GEMM).
// R4: depth-3 counted-vmcnt pipeline (~35us/GEMM). 1 block/CU.
// R5: BN=64/BK=32, 512 blocks = 2/CU. 247us.
// R6: LDS-repacked 16B-store epilogue + setprio(1). 219us.
// R7/R9: one barrier per K-step (4 bufs) - neutral (221us).
// R10: B global->reg streaming FAILED (4x overfetch, 85us/GEMM).
// R11: cooperative all-in-one FAILED (grid.sync + TLP-starved prep, 1105us).
// R12: depth-5 prefetch, 6 LDS buffers (72KB, still 2 blocks/CU):
//      ~4 steps (~900cy) of latency cover vs depth-3's ~2 steps.

#define DD 2048
#define DEPTH 9

#define BM 128
#define BN 64
#define BK 32
#define NT (DD / BK)     // 64 K-tiles
#define ABUF (BM * BK)   // elements per A LDS buffer
#define BBUF (BN * BK)   // elements per B LDS buffer
#define NBUF 6

typedef __attribute__((ext_vector_type(8))) short short8;
typedef __attribute__((ext_vector_type(4))) float f32x4;

__device__ __forceinline__ unsigned short f2bf(float f) {
  unsigned u = __float_as_uint(f);
  u += 0x7FFFu + ((u >> 16) & 1u);   // round-to-nearest-even
  return (unsigned short)(u >> 16);
}

// ---------------- fused prep kernel ----------------
// blocks [0,8192): transpose w0,w1 -> wts[0],wts[1]  (bf16 [N][K])
// blocks [8192,12288): cvt x -> bf16
// blocks [12288,12304): padd for both infinite layers
__global__ __launch_bounds__(256) void prep_kernel(
    const float* __restrict__ w0, const float* __restrict__ w1,
    unsigned short* __restrict__ wts, const float* __restrict__ x,
    unsigned short* __restrict__ xb, const float* __restrict__ infw1,
    const float* __restrict__ infw2, const float* __restrict__ clsb1,
    const float* __restrict__ clsb2, float* __restrict__ padd1,
    float* __restrict__ padd2) {
  int b = blockIdx.x;
  int tid = threadIdx.x;
  if (b < 8192) {
    __shared__ float tile[32][33];
    int z = b >> 12;              // 0: w0, 1: w1
    int t = b & 4095;
    const float* src = z ? w1 : w0;
    unsigned short* dst = wts + (size_t)z * DD * DD;
    int bx = (t & 63) * 32;       // n base
    int by = (t >> 6) * 32;       // k base
    int tx = tid & 31, ty = tid >> 5;
#pragma unroll
    for (int i = ty; i < 32; i += 8)
      tile[i][tx] = src[(size_t)(by + i) * DD + bx + tx];
    __syncthreads();
#pragma unroll
    for (int i = ty; i < 32; i += 8)
      dst[(size_t)(bx + i) * DD + by + tx] = f2bf(tile[tx][i]);
  } else if (b < 12288) {
    int i = (b - 8192) * 256 + tid;       // 1,048,576 float4 chunks
    float4 v = reinterpret_cast<const float4*>(x)[i];
    ushort4 o;
    o.x = f2bf(v.x); o.y = f2bf(v.y); o.z = f2bf(v.z); o.w = f2bf(v.w);
    reinterpret_cast<ushort4*>(xb)[i] = o;
  } else {
    int jj = (b - 12288) * 256 + tid;     // 0..4095
    int layer = jj >> 11;
    int j = jj & 2047;
    const float* inf_w = layer ? infw2 : infw1;
    const float* cls_b = layer ? clsb2 : clsb1;
    float* padd = layer ? padd2 : padd1;
    float prod = 1.0f;
#pragma unroll
    for (int d = 0; d < DEPTH; ++d) {
      const float* row = inf_w + ((size_t)d * DD + j) * DD;
      prod *= cosf(row[0]) * cosf(row[1]) * cosf(row[2]);
    }
    padd[j] = cls_b[j] + prod * prod * (1.0f / (float)DD);
  }
}

// ---------------- GEMM ----------------

__device__ __forceinline__ void gload_lds16(const unsigned short* g,
                                            unsigned short* l) {
  __builtin_amdgcn_global_load_lds(
      (const __attribute__((address_space(1))) void*)g,
      (__attribute__((address_space(3))) void*)l, 16, 0, 0);
}

// EPI: 0 = relu -> bf16, 1 = tanh -> bf16, 2 = relu -> f32
// A: [M][K] bf16 row-major. Bt: [N][K] bf16 (transposed weight). bias: [N].
// tsrc/tdst: optional weight transpose tail (for a LATER gemm's weight).
template <int EPI>
__global__ __launch_bounds__(256) void gemm_kernel(
    const unsigned short* __restrict__ A, const unsigned short* __restrict__ Bt,
    const float* __restrict__ bias, unsigned short* __restrict__ Cb,
    float* __restrict__ Cf, const float* __restrict__ tsrc,
    unsigned short* __restrict__ tdst) {
  const int N = DD, K = DD;
  // 72KB union: 6 pipeline buffer pairs (6 x (8KB A + 4KB B)) /
  // epilogue f32 tile (128*68*4 = 34816B) / tail transpose (64*65*4).
  __shared__ __align__(16) unsigned char smem[73728];
  unsigned short* As = (unsigned short*)smem;                    // 6 x 4096 el
  unsigned short* Bs = (unsigned short*)(smem + NBUF * ABUF * 2);// 6 x 2048 el

  int tid = threadIdx.x;
  int wid = tid >> 6, lane = tid & 63;
  int wr = wid >> 1, wc = wid & 1;   // wave grid 2x2, wave tile 64x32
  int lr = lane & 15;
  int lg = lane >> 4;

  // XCD-aware bijective swizzle over 512 blocks (512 % 8 == 0).
  int bid = blockIdx.x;
  int swz = (bid & 7) * 64 + (bid >> 3);
  int bcol = (swz & 31) * BN;   // 32 n-tiles
  int brow = (swz >> 5) * BM;   // 16 m-tiles

  const unsigned short* Abase = A + (size_t)brow * K;
  const unsigned short* Bbase = Bt + (size_t)bcol * K;

  // Staging (rule 21): LDS dest linear; SOURCE slot pre-swizzled with the
  // same involution the reader applies: slot' = slot ^ ((row>>1)&3).
  // 3 gload_lds per thread per tile (2 A + 1 B) -> vmcnt units.
  auto stage = [&](int buf, int tile) {
    int kt = tile * BK;
#pragma unroll
    for (int r = 0; r < 2; ++r) {
      int chunk = r * 256 + tid;          // 0..511 (A: 128 rows x 4 slots)
      int row = chunk >> 2;
      int sp = chunk & 3;
      int kof = (sp ^ ((row >> 1) & 3)) * 8;
      gload_lds16(Abase + (size_t)row * K + kt + kof,
                  As + buf * ABUF + (size_t)(r * 256 + wid * 64) * 8);
    }
    {
      int row = tid >> 2;                 // B: 64 rows x 4 slots
      int sp = tid & 3;
      int kof = (sp ^ ((row >> 1) & 3)) * 8;
      gload_lds16(Bbase + (size_t)row * K + kt + kof,
                  Bs + buf * BBUF + (size_t)(wid * 64) * 8);
    }
  };

  f32x4 acc[4][2];
#pragma unroll
  for (int i = 0; i < 4; ++i)
#pragma unroll
    for (int j = 0; j < 2; ++j) acc[i][j] = f32x4{0.f, 0.f, 0.f, 0.f};

  auto compute = [&](int buf) {
    short8 a[4], b[2];
#pragma unroll
    for (int mt = 0; mt < 4; ++mt) {
      int row = wr * 64 + mt * 16 + lr;
      int slot = lg ^ ((row >> 1) & 3);
      a[mt] = *reinterpret_cast<const short8*>(
          &As[buf * ABUF + row * BK + slot * 8]);
    }
#pragma unroll
    for (int nt = 0; nt < 2; ++nt) {
      int row = wc * 32 + nt * 16 + lr;
      int slot = lg ^ ((row >> 1) & 3);
      b[nt] = *reinterpret_cast<const short8*>(
          &Bs[buf * BBUF + row * BK + slot * 8]);
    }
    __builtin_amdgcn_s_setprio(1);         // T5: favor MFMA-entering wave
#pragma unroll
    for (int mt = 0; mt < 4; ++mt)
#pragma unroll
      for (int nt = 0; nt < 2; ++nt)
        acc[mt][nt] = __builtin_amdgcn_mfma_f32_16x16x32_bf16(
            a[mt], b[nt], acc[mt][nt], 0, 0, 0);
    __builtin_amdgcn_s_setprio(0);
  };

  // ONE barrier per step (R9-verified). 6 buffers, tile t in buf t%6.
  // Stage target (t+5)%6 == (t-1)%6: read-drained by the step-t barrier.
  // Steady-state: tiles t..t+4 outstanding (15 loads); wait vmcnt(12)
  // completes tile t while 4 newer tiles (~900cy of cover) stay in flight.
  // wcase: 0->12, 1->9, 2->6, 3->3, 4->0.
  auto step = [&](int buf, int pf_tile, int wcase) {
    if (wcase == 0) asm volatile("s_waitcnt vmcnt(12)" ::: "memory");
    else if (wcase == 1) asm volatile("s_waitcnt vmcnt(9)" ::: "memory");
    else if (wcase == 2) asm volatile("s_waitcnt vmcnt(6)" ::: "memory");
    else if (wcase == 3) asm volatile("s_waitcnt vmcnt(3)" ::: "memory");
    else asm volatile("s_waitcnt vmcnt(0)" ::: "memory");
    __builtin_amdgcn_s_barrier();          // buffer `buf` fully written
    __builtin_amdgcn_sched_barrier(0);
    compute(buf);
    if (pf_tile < NT) stage(pf_tile % NBUF, pf_tile);
  };

  // Prologue: depth-5 (tiles 0..4 in flight, 15 loads/thread).
  stage(0, 0); stage(1, 1); stage(2, 2); stage(3, 3); stage(4, 4);
#pragma unroll 1
  for (int i = 0; i < 10; ++i) {           // steps 0..59
    int t = 6 * i;
    step(0, t + 5, 0);
    step(1, t + 6, 0);
    step(2, t + 7, 0);
    step(3, t + 8, 0);
    step(4, t + 9, 0);
    step(5, t + 10, 0);
  }
  step(0, NT, 1);                          // step 60: vmcnt(9)
  step(1, NT, 2);                          // step 61: vmcnt(6)
  step(2, NT, 3);                          // step 62: vmcnt(3)
  step(3, NT, 4);                          // step 63: vmcnt(0)

  // ---- epilogue: LDS-repack to coalesced 16B stores.
  // C/D layout col=lane&15, row=(lane>>4)*4+reg [m89-verified].
  {
    float* et = reinterpret_cast<float*>(smem);   // [128][68] f32
    __syncthreads();                              // pipeline LDS dead now
#pragma unroll
    for (int nt = 0; nt < 2; ++nt) {
      int colb = wc * 32 + nt * 16 + lr;
      float bs = bias[bcol + colb];
#pragma unroll
      for (int mt = 0; mt < 4; ++mt) {
#pragma unroll
        for (int i = 0; i < 4; ++i) {
          int rowb = wr * 64 + mt * 16 + lg * 4 + i;
          float v = acc[mt][nt][i] + bs;
          v = (EPI == 1) ? tanhf(v) : fmaxf(v, 0.0f);
          et[rowb * 68 + colb] = v;
        }
      }
    }
    __syncthreads();
#pragma unroll
    for (int it = 0; it < 4; ++it) {
      int chunk = it * 256 + tid;          // 1024 chunks of 8 elements
      int rowb = chunk >> 3;
      int c8 = (chunk & 7) * 8;
      float4 v0 = *reinterpret_cast<const float4*>(&et[rowb * 68 + c8]);
      float4 v1 = *reinterpret_cast<const float4*>(&et[rowb * 68 + c8 + 4]);
      size_t g = (size_t)(brow + rowb) * N + bcol + c8;
      if (EPI == 2) {
        *reinterpret_cast<float4*>(&Cf[g]) = v0;
        *reinterpret_cast<float4*>(&Cf[g + 4]) = v1;
      } else {
        uint4 o;
        o.x = (unsigned)f2bf(v0.x) | ((unsigned)f2bf(v0.y) << 16);
        o.y = (unsigned)f2bf(v0.z) | ((unsigned)f2bf(v0.w) << 16);
        o.z = (unsigned)f2bf(v1.x) | ((unsigned)f2bf(v1.y) << 16);
        o.w = (unsigned)f2bf(v1.z) | ((unsigned)f2bf(v1.w) << 16);
        *reinterpret_cast<uint4*>(&Cb[g]) = o;
      }
    }
  }

  // ---- transpose tail: tdst[n*D+k] = bf16(tsrc[k*D+n]) for a later GEMM.
  // 1024 64x64 tiles over 512 blocks = 2 tiles/block.
  if (tsrc != nullptr) {
    float* ft = reinterpret_cast<float*>(smem);  // 64*65 f32 = 16.6KB
    __syncthreads();
#pragma unroll 1
    for (int t2 = 0; t2 < 2; ++t2) {
      int tau = bid * 2 + t2;
      int bx = (tau & 31) * 64;   // n base
      int by = (tau >> 5) * 64;   // k base
      if (t2) __syncthreads();
#pragma unroll
      for (int it = 0; it < 4; ++it) {
        int idx = it * 256 + tid;
        int r = idx >> 4, c4 = (idx & 15) * 4;
        float4 v = *reinterpret_cast<const float4*>(
            &tsrc[(size_t)(by + r) * DD + bx + c4]);
        ft[r * 65 + c4 + 0] = v.x;
        ft[r * 65 + c4 + 1] = v.y;
        ft[r * 65 + c4 + 2] = v.z;
        ft[r * 65 + c4 + 3] = v.w;
      }
      __syncthreads();
#pragma unroll
      for (int it = 0; it < 4; ++it) {
        int idx = it * 256 + tid;
        int n = idx >> 4, kq = idx & 15;
        ushort4 o;
        o.x = f2bf(ft[(kq * 4 + 0) * 65 + n]);
        o.y = f2bf(ft[(kq * 4 + 1) * 65 + n]);
        o.z = f2bf(ft[(kq * 4 + 2) * 65 + n]);
        o.w = f2bf(ft[(kq * 4 + 3) * 65 + n]);
        *reinterpret_cast<ushort4*>(&tdst[(size_t)(bx + n) * DD + by + kq * 4]) = o;
      }
    }
  }
}

// ---------------- launch ----------------

extern "C" void kernel_launch(void* const* d_in, const int* in_sizes, int n_in,
                              void* d_out, int out_size, void* d_ws,
                              size_t ws_size, hipStream_t stream) {
  const float* x     = (const float*)d_in[0];
  const float* w0    = (const float*)d_in[1];
  const float* b0    = (const float*)d_in[2];
  const float* w1    = (const float*)d_in[3];
  const float* b1    = (const float*)d_in[4];
  const float* infw1 = (const float*)d_in[5];
  const float* clsw1 = (const float*)d_in[6];
  const float* clsb1 = (const float*)d_in[7];
  const float* w2    = (const float*)d_in[8];
  const float* b2    = (const float*)d_in[9];
  const float* infw2 = (const float*)d_in[10];
  const float* clsw2 = (const float*)d_in[11];
  const float* clsb2 = (const float*)d_in[12];
  const float* w3    = (const float*)d_in[13];
  const float* b3    = (const float*)d_in[14];
  float* out = (float*)d_out;

  char* ws = (char*)d_ws;
  const size_t MB = 1ull << 20;
  const size_t DDe = (size_t)DD * DD;
  unsigned short* buf0 = (unsigned short*)ws;              // 8 MB (x_bf16 / act)
  unsigned short* buf1 = (unsigned short*)(ws + 8 * MB);   // 8 MB (act)
  unsigned short* wts  = (unsigned short*)(ws + 16 * MB);  // 6 x 8 MB
  float* padd1 = (float*)(ws + 64 * MB);
  float* padd2 = padd1 + DD;

  prep_kernel<<<12304, 256, 0, stream>>>(w0, w1, wts, x, buf0, infw1, infw2,
                                         clsb1, clsb2, padd1, padd2);

  dim3 gg((DD / BM) * (DD / BN));  // 512 blocks -> 2 blocks/CU
  // GEMM_i tail-transposes the weight consumed by GEMM_{i+2} (stream order
  // guarantees GEMM_i completes before GEMM_{i+1} starts).
  gemm_kernel<0><<<gg, 256, 0, stream>>>(buf0, wts + 0 * DDe, b0,    buf1,
                                         nullptr, clsw1, wts + 2 * DDe);
  gemm_kernel<0><<<gg, 256, 0, stream>>>(buf1, wts + 1 * DDe, b1,    buf0,
                                         nullptr, w2,    wts + 3 * DDe);
  gemm_kernel<1><<<gg, 256, 0, stream>>>(buf0, wts + 2 * DDe, padd1, buf1,
                                         nullptr, clsw2, wts + 4 * DDe);
  gemm_kernel<0><<<gg, 256, 0, stream>>>(buf1, wts + 3 * DDe, b2,    buf0,
                                         nullptr, w3,    wts + 5 * DDe);
  gemm_kernel<1><<<gg, 256, 0, stream>>>(buf0, wts + 4 * DDe, padd2, buf1,
                                         nullptr, nullptr, nullptr);
  gemm_kernel<2><<<gg, 256, 0, stream>>>(buf1, wts + 5 * DDe, b3,    nullptr,
                                         out, nullptr, nullptr);
}